// Round 5
// baseline (132.644 us; speedup 1.0000x reference)
//
#include <hip/hip_runtime.h>
#include <math.h>

// Filtered Back Projection, B=2, A=181, L=512, P=1024.
// ws layout (floats):
//   [0,1024)        filt
//   [1024,2048)     hr (real impulse response)
//   [2048,2229)     cth = cos(angle + pi/2)
//   [2304,2485)     sth = sin(angle + pi/2)
//   [4096,189440)   sino_f interleaved: [a][pos][{img0,img1}]  (181*512*2)
#define OFF_FILT 0
#define OFF_HR   1024
#define OFF_CTH  2048
#define OFF_STH  2304
#define OFF_SF   4096

// cos(2*pi*x) -- v_cos_f32 takes revolutions
__device__ __forceinline__ float cos2pi(float x) {
  return __builtin_amdgcn_cosf(x);
}

// ---- filt[k] = ramp[k]*hann_shift[k]; wave-per-output, v_cos phases -------
// Also zeroes d_out (atomic accumulation target for k_bp).
__global__ __launch_bounds__(256) void k_filt(const float* __restrict__ angles,
                                              float* __restrict__ ws,
                                              float* __restrict__ out) {
  const int t = threadIdx.x & 63;
  const int k = blockIdx.x * 4 + (threadIdx.x >> 6);   // 0..1023
  float acc = 0.f;
#pragma unroll
  for (int q = 0; q < 8; q++) {
    int tt = t + 64 * q;
    int n = (tt < 256) ? (2 * tt + 1) : (1023 - 2 * tt);
    float pin = 3.14159265358979f * (float)n;
    float cf = -1.0f / (pin * pin);
    int r = ((2 * tt + 1) * k) & 1023;
    acc = fmaf(cf, cos2pi((float)r * (1.0f / 1024.0f)), acc);
  }
#pragma unroll
  for (int o = 32; o; o >>= 1) acc += __shfl_down(acc, o, 64);
  if (t == 0) {
    float ramp = 0.5f + 2.0f * acc;
    int ks = (k + 512) & 1023;                         // fftshift
    float hann = 0.5f - 0.5f * cos2pi((float)ks * (1.0f / 1023.0f));
    ws[OFF_FILT + k] = ramp * hann;
  }
  if (blockIdx.x == 0 && threadIdx.x < 181) {          // angle trig
    float th = angles[threadIdx.x] + 1.5707963267948966f;
    ws[OFF_CTH + threadIdx.x] = cosf(th);
    ws[OFF_STH + threadIdx.x] = sinf(th);
  }
  // zero d_out: 2*512*512 floats = 131072 float4, 65536 threads x 2
  const float4 z4 = make_float4(0.f, 0.f, 0.f, 0.f);
  float4* o4 = (float4*)out;
  int idx = blockIdx.x * 256 + threadIdx.x;
  o4[idx] = z4;
  o4[idx + 65536] = z4;
}

// ---- hr[m] = (1/1024) sum_k filt[k] cos(2*pi*k*m/1024); wave-per-output ---
__global__ __launch_bounds__(256) void k_hr(float* __restrict__ ws) {
  const int t = threadIdx.x & 63;
  const int m = blockIdx.x * 4 + (threadIdx.x >> 6);   // 0..1023
  float acc = 0.f;
  int r = (t * m) & 1023;
  const int step = (64 * m) & 1023;
#pragma unroll
  for (int q = 0; q < 16; q++) {
    acc = fmaf(ws[OFF_FILT + t + 64 * q],
               cos2pi((float)r * (1.0f / 1024.0f)), acc);
    r = (r + step) & 1023;
  }
#pragma unroll
  for (int o = 32; o; o >>= 1) acc += __shfl_down(acc, o, 64);
  if (t == 0) ws[OFF_HR + m] = acc * (1.0f / 1024.0f);
}

// ---- row circular conv, BOTH planes per block, interleaved output ---------
// grid (181 angles, 2 position-halves), 64 thr x 4 positions x 2 images.
__global__ __launch_bounds__(64) void k_conv(const float* __restrict__ sino,
                                             float* __restrict__ ws) {
  __shared__ float s_s0[512];
  __shared__ float s_s1[512];
  __shared__ float s_hr[1024];
  const int t = threadIdx.x;
  const int a = blockIdx.x;         // 0..180
  const float4* r0 = (const float4*)(sino + (size_t)a * 512);
  const float4* r1 = (const float4*)(sino + (size_t)(181 + a) * 512);
  ((float4*)s_s0)[t] = r0[t];
  ((float4*)s_s0)[t + 64] = r0[t + 64];
  ((float4*)s_s1)[t] = r1[t];
  ((float4*)s_s1)[t + 64] = r1[t + 64];
  const float4* hr4 = (const float4*)(ws + OFF_HR);
#pragma unroll
  for (int q = 0; q < 4; q++) ((float4*)s_hr)[t + 64 * q] = hr4[t + 64 * q];
  __syncthreads();

  const int base = blockIdx.y * 256 + t * 4;   // 4 output positions
  float acc0[4] = {0.f, 0.f, 0.f, 0.f};
  float acc1[4] = {0.f, 0.f, 0.f, 0.f};
  const float4* SH = (const float4*)s_hr;
  const float4* S0 = (const float4*)s_s0;
  const float4* S1 = (const float4*)s_s1;
  for (int j8 = 0; j8 < 512; j8 += 8) {
    float4 sa0 = S0[j8 >> 2];
    float4 sb0 = S0[(j8 >> 2) + 1];
    float4 sa1 = S1[j8 >> 2];
    float4 sb1 = S1[(j8 >> 2) + 1];
    int w = base - j8;
    float4 h0 = SH[((w - 8) & 1023) >> 2];
    float4 h1 = SH[((w - 4) & 1023) >> 2];
    float4 h2 = SH[(w & 1023) >> 2];
    float qq[12] = {h0.x, h0.y, h0.z, h0.w, h1.x, h1.y,
                    h1.z, h1.w, h2.x, h2.y, h2.z, h2.w};
    float v0[8] = {sa0.x, sa0.y, sa0.z, sa0.w, sb0.x, sb0.y, sb0.z, sb0.w};
    float v1[8] = {sa1.x, sa1.y, sa1.z, sa1.w, sb1.x, sb1.y, sb1.z, sb1.w};
#pragma unroll
    for (int jj = 0; jj < 8; jj++) {
#pragma unroll
      for (int m = 0; m < 4; m++) {
        acc0[m] = fmaf(v0[jj], qq[8 + m - jj], acc0[m]);
        acc1[m] = fmaf(v1[jj], qq[8 + m - jj], acc1[m]);
      }
    }
  }
  // interleaved write: float index OFF_SF + a*1024 + base*2 + 2*p + img
  float* dst = ws + OFF_SF + (size_t)a * 1024 + base * 2;
  ((float4*)dst)[0] = make_float4(acc0[0], acc1[0], acc0[1], acc1[1]);
  ((float4*)dst)[1] = make_float4(acc0[2], acc1[2], acc0[3], acc1[3]);
}

// ---- backprojection -------------------------------------------------------
// grid (256, 2): x = output ROW PAIR (rows 2bx, 2bx+1), y = angle half.
// Two rows per block: the staged chunk is reused for 2x the pixels (staging
// LDS writes + global fetches halve) and the 2nd row's coordinate is free
// (u1 = u0 + c). CHUNK=12 (69.9 KB LDS, 2 blocks/CU) -> only 8 chunks = 16
// barriers per block. Rows staged as float2 {img0,img1} with zero guard
// bands covering the full i0 range (OOB taps read 0 == reference's zeroed
// weights). Register-prefetch pipeline: chunk c+1's 6 float4s load while
// chunk c is consumed.
#define PAD   108
#define ROWE  728          // PAD + 512 + PAD
#define CHUNK 12           // 12*728*8 = 69888 B LDS -> 2 blocks/CU
__global__ __launch_bounds__(512, 4) void k_bp(const float* __restrict__ ws,
                                               const int* __restrict__ circ,
                                               float* __restrict__ out) {
  __shared__ float2 srow[CHUNK * ROWE];
  const int j = threadIdx.x;
  const int i0 = blockIdx.x * 2;               // rows i0, i0+1
  const int abase = blockIdx.y * 91;
  const int acnt = min(91, 181 - abase);       // 91 or 90
  const float xc = (float)(i0 - 256);
  const float yc = (float)(j - 256);
  const float* __restrict__ cth = ws + OFF_CTH;
  const float* __restrict__ sth = ws + OFF_STH;
  float a00 = 0.f, a01 = 0.f, a10 = 0.f, a11 = 0.f;   // [row][img]

  // zero guard bands once; interior rewritten every chunk
  const float2 z2 = make_float2(0.f, 0.f);
#pragma unroll
  for (int r = 0; r < CHUNK; r++) {
    if (j < PAD) srow[r * ROWE + j] = z2;
    if (j < ROWE - PAD - 512) srow[r * ROWE + PAD + 512 + j] = z2;
  }

  // staging: 12 rows x 256 float4 = 3072 slots; thread j owns slots
  // j + 512q (q=0..5) -> row (j>>8)+2q, col j&255 (const per thread).
  const int rb = j >> 8;
  const int col = j & 255;
  const float4* __restrict__ G = (const float4*)(ws + OFF_SF);
  const int rowcap = abase + acnt - 1;

  int A = abase;
  float4 pre[6];
#pragma unroll
  for (int q = 0; q < 6; q++)
    pre[q] = G[min(A + rb + 2 * q, rowcap) * 256 + col];

  for (int c = 0; c < 8; c++) {
    __syncthreads();                 // previous chunk fully consumed
#pragma unroll
    for (int q = 0; q < 6; q++)
      *(float4*)&srow[(rb + 2 * q) * ROWE + PAD + 2 * col] = pre[q];
    const int An = A + CHUNK;
    if (c < 7) {                     // prefetch next chunk (latency hidden)
#pragma unroll
      for (int q = 0; q < 6; q++)
        pre[q] = G[min(An + rb + 2 * q, rowcap) * 256 + col];
    }
    __syncthreads();                 // writes visible
    const int nv = min(CHUNK, abase + acnt - A);
#pragma unroll
    for (int r = 0; r < CHUNK; r++) {
      if (r >= nv) break;
      const int a = A + r;
      const float c_ = cth[a];       // uniform -> scalar loads
      const float s_ = sth[a];
      float u0 = fmaf(xc, c_, fmaf(yc, s_, 255.5f + (float)PAD));
      float u1 = u0 + c_;            // next row: xc+1
      float fl0 = floorf(u0), fl1 = floorf(u1);
      float fr0 = u0 - fl0, fr1 = u1 - fl1;
      int b0 = (int)fl0, b1 = (int)fl1;   // in [1,725] by construction
      const float2* rp = &srow[r * ROWE];
      float2 p00 = rp[b0];
      float2 p01 = rp[b0 + 1];
      float2 p10 = rp[b1];
      float2 p11 = rp[b1 + 1];
      float w0 = 1.0f - fr0, w1 = 1.0f - fr1;
      a00 = fmaf(w0, p00.x, fmaf(fr0, p01.x, a00));
      a01 = fmaf(w0, p00.y, fmaf(fr0, p01.y, a01));
      a10 = fmaf(w1, p10.x, fmaf(fr1, p11.x, a10));
      a11 = fmaf(w1, p10.y, fmaf(fr1, p11.y, a11));
    }
    A = An;
  }

  const int dx = j - 256;
  const bool con = (circ[0] != 0);
  const int dy0 = i0 - 256, dy1 = i0 + 1 - 256;
  const size_t o0 = (size_t)i0 * 512 + j;
  if (!(con && dx * dx + dy0 * dy0 > 65536)) {
    atomicAdd(&out[o0], a00);
    atomicAdd(&out[262144 + o0], a01);
  }
  if (!(con && dx * dx + dy1 * dy1 > 65536)) {
    atomicAdd(&out[o0 + 512], a10);
    atomicAdd(&out[262144 + o0 + 512], a11);
  }
}

extern "C" void kernel_launch(void* const* d_in, const int* in_sizes, int n_in,
                              void* d_out, int out_size, void* d_ws, size_t ws_size,
                              hipStream_t stream) {
  const float* sino = (const float*)d_in[0];    // (2,181,512) f32
  const float* angles = (const float*)d_in[1];  // (181,) f32
  const int* circ = (const int*)d_in[2];        // scalar int
  float* ws = (float*)d_ws;                     // ~758 KB used
  float* out = (float*)d_out;                   // (2,512,512) f32

  hipLaunchKernelGGL(k_filt, dim3(256),    dim3(256), 0, stream, angles, ws, out);
  hipLaunchKernelGGL(k_hr,   dim3(256),    dim3(256), 0, stream, ws);
  hipLaunchKernelGGL(k_conv, dim3(181, 2), dim3(64),  0, stream, sino, ws);
  hipLaunchKernelGGL(k_bp,   dim3(256, 2), dim3(512), 0, stream, ws, circ, out);
}

// Round 6
// 96.628 us; speedup vs baseline: 1.3727x; 1.3727x over previous
//
#include <hip/hip_runtime.h>
#include <math.h>

// Filtered Back Projection, B=2, A=181, L=512, P=1024.
// ws layout (floats):
//   [0,1024)          filt
//   [1024,2048)       hr (real impulse response)
//   [2048,2229)       cth = cos(angle + pi/2)
//   [2304,2485)       sth = sin(angle + pi/2)
//   [4096,189440)     sino_f interleaved: [a][pos][{img0,img1}] (181*512*2)
//   [189440,2286592)  4 partial-sum buffers, each 524288 floats ([img][i][j])
#define OFF_FILT 0
#define OFF_HR   1024
#define OFF_CTH  2048
#define OFF_STH  2304
#define OFF_SF   4096
#define OFF_P    189440
#define WS_NEED  (2286592ull * 4ull)

// cos(2*pi*x) -- v_cos_f32 takes revolutions
__device__ __forceinline__ float cos2pi(float x) {
  return __builtin_amdgcn_cosf(x);
}

// ---- filt[k] = ramp[k]*hann_shift[k]; wave-per-output, v_cos phases -------
// Also zeroes d_out (needed by the atomic fallback; harmless otherwise).
__global__ __launch_bounds__(256) void k_filt(const float* __restrict__ angles,
                                              float* __restrict__ ws,
                                              float* __restrict__ out) {
  const int t = threadIdx.x & 63;
  const int k = blockIdx.x * 4 + (threadIdx.x >> 6);   // 0..1023
  float acc = 0.f;
#pragma unroll
  for (int q = 0; q < 8; q++) {
    int tt = t + 64 * q;
    int n = (tt < 256) ? (2 * tt + 1) : (1023 - 2 * tt);
    float pin = 3.14159265358979f * (float)n;
    float cf = -1.0f / (pin * pin);
    int r = ((2 * tt + 1) * k) & 1023;
    acc = fmaf(cf, cos2pi((float)r * (1.0f / 1024.0f)), acc);
  }
#pragma unroll
  for (int o = 32; o; o >>= 1) acc += __shfl_down(acc, o, 64);
  if (t == 0) {
    float ramp = 0.5f + 2.0f * acc;
    int ks = (k + 512) & 1023;                         // fftshift
    float hann = 0.5f - 0.5f * cos2pi((float)ks * (1.0f / 1023.0f));
    ws[OFF_FILT + k] = ramp * hann;
  }
  if (blockIdx.x == 0 && threadIdx.x < 181) {          // angle trig
    float th = angles[threadIdx.x] + 1.5707963267948966f;
    ws[OFF_CTH + threadIdx.x] = cosf(th);
    ws[OFF_STH + threadIdx.x] = sinf(th);
  }
  const float4 z4 = make_float4(0.f, 0.f, 0.f, 0.f);
  float4* o4 = (float4*)out;
  int idx = blockIdx.x * 256 + threadIdx.x;
  o4[idx] = z4;
  o4[idx + 65536] = z4;
}

// ---- hr[m] = (1/1024) sum_k filt[k] cos(2*pi*k*m/1024); wave-per-output ---
__global__ __launch_bounds__(256) void k_hr(float* __restrict__ ws) {
  const int t = threadIdx.x & 63;
  const int m = blockIdx.x * 4 + (threadIdx.x >> 6);   // 0..1023
  float acc = 0.f;
  int r = (t * m) & 1023;
  const int step = (64 * m) & 1023;
#pragma unroll
  for (int q = 0; q < 16; q++) {
    acc = fmaf(ws[OFF_FILT + t + 64 * q],
               cos2pi((float)r * (1.0f / 1024.0f)), acc);
    r = (r + step) & 1023;
  }
#pragma unroll
  for (int o = 32; o; o >>= 1) acc += __shfl_down(acc, o, 64);
  if (t == 0) ws[OFF_HR + m] = acc * (1.0f / 1024.0f);
}

// ---- row circular conv, BOTH planes per block, interleaved output ---------
// grid (181 angles, 2 position-halves), 64 thr x 4 positions x 2 images.
__global__ __launch_bounds__(64) void k_conv(const float* __restrict__ sino,
                                             float* __restrict__ ws) {
  __shared__ float s_s0[512];
  __shared__ float s_s1[512];
  __shared__ float s_hr[1024];
  const int t = threadIdx.x;
  const int a = blockIdx.x;         // 0..180
  const float4* r0 = (const float4*)(sino + (size_t)a * 512);
  const float4* r1 = (const float4*)(sino + (size_t)(181 + a) * 512);
  ((float4*)s_s0)[t] = r0[t];
  ((float4*)s_s0)[t + 64] = r0[t + 64];
  ((float4*)s_s1)[t] = r1[t];
  ((float4*)s_s1)[t + 64] = r1[t + 64];
  const float4* hr4 = (const float4*)(ws + OFF_HR);
#pragma unroll
  for (int q = 0; q < 4; q++) ((float4*)s_hr)[t + 64 * q] = hr4[t + 64 * q];
  __syncthreads();

  const int base = blockIdx.y * 256 + t * 4;   // 4 output positions
  float acc0[4] = {0.f, 0.f, 0.f, 0.f};
  float acc1[4] = {0.f, 0.f, 0.f, 0.f};
  const float4* SH = (const float4*)s_hr;
  const float4* S0 = (const float4*)s_s0;
  const float4* S1 = (const float4*)s_s1;
  for (int j8 = 0; j8 < 512; j8 += 8) {
    float4 sa0 = S0[j8 >> 2];
    float4 sb0 = S0[(j8 >> 2) + 1];
    float4 sa1 = S1[j8 >> 2];
    float4 sb1 = S1[(j8 >> 2) + 1];
    int w = base - j8;
    float4 h0 = SH[((w - 8) & 1023) >> 2];
    float4 h1 = SH[((w - 4) & 1023) >> 2];
    float4 h2 = SH[(w & 1023) >> 2];
    float qq[12] = {h0.x, h0.y, h0.z, h0.w, h1.x, h1.y,
                    h1.z, h1.w, h2.x, h2.y, h2.z, h2.w};
    float v0[8] = {sa0.x, sa0.y, sa0.z, sa0.w, sb0.x, sb0.y, sb0.z, sb0.w};
    float v1[8] = {sa1.x, sa1.y, sa1.z, sa1.w, sb1.x, sb1.y, sb1.z, sb1.w};
#pragma unroll
    for (int jj = 0; jj < 8; jj++) {
#pragma unroll
      for (int m = 0; m < 4; m++) {
        acc0[m] = fmaf(v0[jj], qq[8 + m - jj], acc0[m]);
        acc1[m] = fmaf(v1[jj], qq[8 + m - jj], acc1[m]);
      }
    }
  }
  float* dst = ws + OFF_SF + (size_t)a * 1024 + base * 2;
  ((float4*)dst)[0] = make_float4(acc0[0], acc1[0], acc0[1], acc1[1]);
  ((float4*)dst)[1] = make_float4(acc0[2], acc1[2], acc0[3], acc1[3]);
}

// ---- backprojection -------------------------------------------------------
// grid (256, 4): x = output ROW PAIR (rows 2bx, 2bx+1), y = angle quarter.
// CHUNK=4 -> 23.3 KB LDS -> 4 blocks/CU (restores R4's occupancy; barrier
// drains hidden by 3 other resident blocks). 2 rows/block: staged chunk
// reused for 1024 pixels, 2nd row's coordinate is free (u1 = u0 + c).
// mode 0: plain-store partials to pbuf (no atomics). mode 1: atomicAdd
// into out with circle mask (fallback if ws too small).
#define PAD   108
#define ROWE  728          // PAD + 512 + PAD
#define CHUNK 4            // 4*728*8 = 23296 B LDS -> 4 blocks/CU
__global__ __launch_bounds__(512) void k_bp(const float* __restrict__ ws,
                                            const int* __restrict__ circ,
                                            float* __restrict__ pbuf,
                                            float* __restrict__ out,
                                            int mode) {
  __shared__ float2 srow[CHUNK * ROWE];
  const int j = threadIdx.x;
  const int i0 = blockIdx.x * 2;               // rows i0, i0+1
  const int by = blockIdx.y;
  const int abase = (by * 181) >> 2;           // 0,45,90,135
  const int aend = ((by + 1) * 181) >> 2;      // 45,90,135,181
  const float xc = (float)(i0 - 256);
  const float yc = (float)(j - 256);
  const float* __restrict__ cth = ws + OFF_CTH;
  const float* __restrict__ sth = ws + OFF_STH;
  float a00 = 0.f, a01 = 0.f, a10 = 0.f, a11 = 0.f;   // [row][img]

  // zero guard bands once; interior rewritten every chunk
  const float2 z2 = make_float2(0.f, 0.f);
#pragma unroll
  for (int r = 0; r < CHUNK; r++) {
    if (j < PAD) srow[r * ROWE + j] = z2;
    if (j < ROWE - PAD - 512) srow[r * ROWE + PAD + 512 + j] = z2;
  }

  // staging: 4 rows x 256 float4 = 1024 slots; thread j owns slots j and
  // j+512 -> rows (j>>8) and (j>>8)+2, col j&255.
  const int rb = j >> 8;
  const int col = j & 255;
  const float4* __restrict__ G = (const float4*)(ws + OFF_SF);
  const int rowcap = aend - 1;
  float4* SW0 = (float4*)&srow[rb * ROWE + PAD + 2 * col];
  float4* SW1 = (float4*)&srow[(rb + 2) * ROWE + PAD + 2 * col];

  int A = abase;
  float4 pre0 = G[min(A + rb, rowcap) * 256 + col];
  float4 pre1 = G[min(A + rb + 2, rowcap) * 256 + col];

  // (45+3)/4 == (46+3)/4 == 12 chunks for every quarter
  for (int c = 0; c < 12; c++) {
    __syncthreads();                 // previous chunk fully consumed
    *SW0 = pre0;
    *SW1 = pre1;
    const int An = A + CHUNK;
    if (c < 11) {                    // prefetch next chunk (latency hidden)
      pre0 = G[min(An + rb, rowcap) * 256 + col];
      pre1 = G[min(An + rb + 2, rowcap) * 256 + col];
    }
    __syncthreads();                 // writes visible
    const int nv = min(CHUNK, aend - A);
#pragma unroll
    for (int r = 0; r < CHUNK; r++) {
      if (r >= nv) break;
      const int a = A + r;
      const float c_ = cth[a];       // uniform -> scalar loads
      const float s_ = sth[a];
      float u0 = fmaf(xc, c_, fmaf(yc, s_, 255.5f + (float)PAD));
      float u1 = u0 + c_;            // next row: xc+1
      float fl0 = floorf(u0), fl1 = floorf(u1);
      float fr0 = u0 - fl0, fr1 = u1 - fl1;
      int b0 = (int)fl0, b1 = (int)fl1;   // in [1,725] by construction
      const float2* rp = &srow[r * ROWE];
      float2 p00 = rp[b0];
      float2 p01 = rp[b0 + 1];
      float2 p10 = rp[b1];
      float2 p11 = rp[b1 + 1];
      float w0 = 1.0f - fr0, w1 = 1.0f - fr1;
      a00 = fmaf(w0, p00.x, fmaf(fr0, p01.x, a00));
      a01 = fmaf(w0, p00.y, fmaf(fr0, p01.y, a01));
      a10 = fmaf(w1, p10.x, fmaf(fr1, p11.x, a10));
      a11 = fmaf(w1, p10.y, fmaf(fr1, p11.y, a11));
    }
    A = An;
  }

  const size_t o0 = (size_t)i0 * 512 + j;
  if (mode == 0) {                   // partial store, no atomics
    float* pb = pbuf + (size_t)by * 524288;
    pb[o0] = a00;
    pb[262144 + o0] = a01;
    pb[o0 + 512] = a10;
    pb[262144 + o0 + 512] = a11;
  } else {                           // atomic fallback
    const int dx = j - 256;
    const bool con = (circ[0] != 0);
    const int dy0 = i0 - 256, dy1 = i0 + 1 - 256;
    if (!(con && dx * dx + dy0 * dy0 > 65536)) {
      atomicAdd(&out[o0], a00);
      atomicAdd(&out[262144 + o0], a01);
    }
    if (!(con && dx * dx + dy1 * dy1 > 65536)) {
      atomicAdd(&out[o0 + 512], a10);
      atomicAdd(&out[262144 + o0 + 512], a11);
    }
  }
}

// ---- sum the 4 partials + circle mask + final store -----------------------
__global__ __launch_bounds__(256) void k_sum(const float* __restrict__ ws,
                                             const int* __restrict__ circ,
                                             float* __restrict__ out) {
  const int idx = blockIdx.x * 256 + threadIdx.x;      // float4 index
  const float4* P0 = (const float4*)(ws + OFF_P);
  const float4* P1 = P0 + 131072;
  const float4* P2 = P1 + 131072;
  const float4* P3 = P2 + 131072;
  float4 v0 = P0[idx], v1 = P1[idx], v2 = P2[idx], v3 = P3[idx];
  float4 v = make_float4(v0.x + v1.x + v2.x + v3.x,
                         v0.y + v1.y + v2.y + v3.y,
                         v0.z + v1.z + v2.z + v3.z,
                         v0.w + v1.w + v2.w + v3.w);
  if (circ[0] != 0) {
    const int f = (idx * 4) & 262143;    // within one image
    const int ii = f >> 9;
    const int jj = f & 511;
    const int dy = ii - 256;
    const int dyy = dy * dy;
    const int d0 = jj - 256;
    if (d0 * d0 + dyy > 65536) v.x = 0.f;
    if ((d0 + 1) * (d0 + 1) + dyy > 65536) v.y = 0.f;
    if ((d0 + 2) * (d0 + 2) + dyy > 65536) v.z = 0.f;
    if ((d0 + 3) * (d0 + 3) + dyy > 65536) v.w = 0.f;
  }
  ((float4*)out)[idx] = v;
}

extern "C" void kernel_launch(void* const* d_in, const int* in_sizes, int n_in,
                              void* d_out, int out_size, void* d_ws, size_t ws_size,
                              hipStream_t stream) {
  const float* sino = (const float*)d_in[0];    // (2,181,512) f32
  const float* angles = (const float*)d_in[1];  // (181,) f32
  const int* circ = (const int*)d_in[2];        // scalar int
  float* ws = (float*)d_ws;
  float* out = (float*)d_out;                   // (2,512,512) f32
  const int partial = (ws_size >= WS_NEED) ? 1 : 0;  // constant across calls

  hipLaunchKernelGGL(k_filt, dim3(256),    dim3(256), 0, stream, angles, ws, out);
  hipLaunchKernelGGL(k_hr,   dim3(256),    dim3(256), 0, stream, ws);
  hipLaunchKernelGGL(k_conv, dim3(181, 2), dim3(64),  0, stream, sino, ws);
  if (partial) {
    hipLaunchKernelGGL(k_bp,  dim3(256, 4), dim3(512), 0, stream,
                       ws, circ, ws + OFF_P, out, 0);
    hipLaunchKernelGGL(k_sum, dim3(512),    dim3(256), 0, stream, ws, circ, out);
  } else {
    hipLaunchKernelGGL(k_bp,  dim3(256, 4), dim3(512), 0, stream,
                       ws, circ, ws + OFF_P, out, 1);
  }
}